// Round 9
// baseline (318.308 us; speedup 1.0000x reference)
//
#include <hip/hip_runtime.h>

#define F 128
#define GRAPHS 64
#define GN_EPS 1e-5f
#define SCAN_B 256

typedef short short8 __attribute__((ext_vector_type(8)));
typedef float f32x4 __attribute__((ext_vector_type(4)));

__device__ __forceinline__ unsigned short f2b(float f) {      // fp32 -> bf16 RNE
    unsigned u = __float_as_uint(f);
    unsigned r = (u + 0x7fffu + ((u >> 16) & 1u)) >> 16;
    return (unsigned short)r;
}
__device__ __forceinline__ float b2f(unsigned short h) {      // bf16 -> fp32
    return __uint_as_float(((unsigned)h) << 16);
}

// ---------------- fused front-end: [deg | f2b | wcvt] (all read only inputs) --------
__global__ void prep_kernel(const int* __restrict__ ei, const float* __restrict__ ew,
                            unsigned long long* __restrict__ packed,
                            unsigned short* __restrict__ rank, int E, int ebl,
                            const float4* __restrict__ y, ushort4* __restrict__ hs0,
                            int n4, int fbl,
                            const float* __restrict__ tw, unsigned short* __restrict__ wf) {
    int b = blockIdx.x;
    if (b < ebl) {                                   // ---- deg ----
        int e = b * 256 + threadIdx.x;
        if (e < E) {
            int dst = ei[E + e];
            unsigned q = (unsigned)(ew[e] * 16777216.0f + 0.5f);
            unsigned long long old =
                atomicAdd(&packed[dst], (1ull << 40) | (unsigned long long)q);
            rank[e] = (unsigned short)(old >> 40);
        }
    } else if (b < ebl + fbl) {                      // ---- f2b ----
        int i = (b - ebl) * 256 + threadIdx.x;
        if (i < n4) {
            float4 v = y[i];
            hs0[i] = make_ushort4(f2b(v.x), f2b(v.y), f2b(v.z), f2b(v.w));
        }
    } else {                                         // ---- wcvt ----
        int i = (b - ebl - fbl) * 256 + threadIdx.x; // over 4*128*128 = 65536
        int seg = i >> 14;
        int r = i & 16383;
        int kb = r >> 12;
        int wc = (r >> 11) & 1;
        int nt = (r >> 9) & 3;
        int lane = (r >> 3) & 63;
        int j = i & 7;
        int k = kb * 32 + (lane >> 4) * 8 + j;
        int n = wc * 64 + nt * 16 + (lane & 15);
        wf[i] = f2b(tw[seg * 16384 + k * 128 + n]);
    }
}

// ---------------- fused: decode packed -> dinv, graph starts, block-local scan ------
__global__ void node_prep_kernel(const unsigned long long* __restrict__ packed,
                                 float* __restrict__ dinv, const int* __restrict__ batch,
                                 int* __restrict__ gstart, int* __restrict__ excl,
                                 int* __restrict__ blockSums, int n) {
    __shared__ int s[SCAN_B];
    int i = blockIdx.x * SCAN_B + threadIdx.x;
    int v = 0;
    if (i < n) {
        unsigned long long p = packed[i];
        v = (int)(p >> 40);
        float d = (float)(p & 0xFFFFFFFFFFull) * 5.9604644775390625e-8f;  // / 2^24
        dinv[i] = (d > 0.f) ? rsqrtf(fmaxf(d, 1e-30f)) : 0.f;
        int b = batch[i];
        if (i == 0) {
            for (int g = 0; g <= b; ++g) gstart[g] = 0;
        } else {
            int bp = batch[i - 1];
            for (int g = bp + 1; g <= b; ++g) gstart[g] = i;
        }
        if (i == n - 1) {
            for (int g = b + 1; g <= GRAPHS; ++g) gstart[g] = n;
        }
    }
    s[threadIdx.x] = v;
    __syncthreads();
    for (int off = 1; off < SCAN_B; off <<= 1) {
        int t = (threadIdx.x >= off) ? s[threadIdx.x - off] : 0;
        __syncthreads();
        s[threadIdx.x] += t;
        __syncthreads();
    }
    if (i < n) excl[i] = s[threadIdx.x] - v;
    if (threadIdx.x == SCAN_B - 1) blockSums[blockIdx.x] = s[SCAN_B - 1];
}

// ---------------- scan3 with inline block-sum scan ----------------
__global__ void scan3_kernel(int* __restrict__ offs, const int* __restrict__ blockSums,
                             int n, int total, int nb) {
    __shared__ int s[SCAN_B];
    int t = threadIdx.x;
    int v = (t < nb) ? blockSums[t] : 0;
    s[t] = v;
    __syncthreads();
    for (int off = 1; off < SCAN_B; off <<= 1) {
        int x = (t >= off) ? s[t - off] : 0;
        __syncthreads();
        s[t] += x;
        __syncthreads();
    }
    int pre = (blockIdx.x == 0) ? 0 : s[blockIdx.x - 1];
    int i = blockIdx.x * SCAN_B + t;
    if (i < n) offs[i] += pre;
    if (i == 0) offs[n] = total;
}

// ---------------- scatter edges into CSR: NO atomics, single 4B write per edge ------
__global__ void scatter_kernel(const int* __restrict__ ei, const float* __restrict__ w,
                               const float* __restrict__ dinv, const int* __restrict__ offs,
                               const unsigned short* __restrict__ rank,
                               unsigned* __restrict__ csr, int E) {
    int e = blockIdx.x * blockDim.x + threadIdx.x;
    if (e >= E) return;
    int s = ei[e];
    int d = ei[E + e];
    unsigned v = ((unsigned)s << 16) | (unsigned)f2b(dinv[s] * w[e]);
    csr[offs[d] + (int)rank[e]] = v;
}

// ---------------- one hop: node-per-wave, 16 edges in flight, 16B gathers -----------
__global__ __launch_bounds__(256) void hop_kernel(const unsigned short* __restrict__ hin,
                                                  unsigned short* __restrict__ hout,
                                                  const int* __restrict__ offs,
                                                  const unsigned* __restrict__ csr,
                                                  const float* __restrict__ dinv, int n) {
    int lane = threadIdx.x & 63;
    int node = blockIdx.x * 4 + (threadIdx.x >> 6);
    if (node >= n) return;
    int g = lane >> 4, fl = lane & 15;
    int e0 = offs[node], e1 = offs[node + 1];
    float acc[8] = {};
    for (int j = e0; j < e1; j += 16) {
        int base = j + g * 4;
        int c0 = min(base + 0, e1 - 1), c1 = min(base + 1, e1 - 1);
        int c2 = min(base + 2, e1 - 1), c3 = min(base + 3, e1 - 1);
        unsigned ed0 = csr[c0], ed1 = csr[c1], ed2 = csr[c2], ed3 = csr[c3];
        float w0 = (base + 0 < e1) ? b2f((unsigned short)(ed0 & 0xffffu)) : 0.f;
        float w1 = (base + 1 < e1) ? b2f((unsigned short)(ed1 & 0xffffu)) : 0.f;
        float w2 = (base + 2 < e1) ? b2f((unsigned short)(ed2 & 0xffffu)) : 0.f;
        float w3 = (base + 3 < e1) ? b2f((unsigned short)(ed3 & 0xffffu)) : 0.f;
        short8 h0 = *(const short8*)(hin + (size_t)(ed0 >> 16) * 128 + fl * 8);
        short8 h1 = *(const short8*)(hin + (size_t)(ed1 >> 16) * 128 + fl * 8);
        short8 h2 = *(const short8*)(hin + (size_t)(ed2 >> 16) * 128 + fl * 8);
        short8 h3 = *(const short8*)(hin + (size_t)(ed3 >> 16) * 128 + fl * 8);
        #pragma unroll
        for (int k = 0; k < 8; ++k) {
            acc[k] += w0 * b2f((unsigned short)h0[k]) + w1 * b2f((unsigned short)h1[k]);
            acc[k] += w2 * b2f((unsigned short)h2[k]) + w3 * b2f((unsigned short)h3[k]);
        }
    }
    #pragma unroll
    for (int k = 0; k < 8; ++k) {
        acc[k] += __shfl_xor(acc[k], 16);
        acc[k] += __shfl_xor(acc[k], 32);
    }
    if (lane < 16) {
        float dd = dinv[node];
        short8 o;
        #pragma unroll
        for (int k = 0; k < 8; ++k) o[k] = (short)f2b(acc[k] * dd);
        *(short8*)(hout + (size_t)node * 128 + fl * 8) = o;
    }
}

// ---------------- fused GEMM + stats: outb(bf16) = hcat @ W + bias; S1/S2 += ---------
// Stats from fp32 accumulators via per-block LDS reduction (graph-slot trick: a
// 64-row block spans <=2 graphs in practice; 4 slots + global-atomic fallback).
__global__ __launch_bounds__(256) void gemm_kernel(const unsigned short* __restrict__ hcat,
                                                   const unsigned short* __restrict__ Wf,
                                                   const float* __restrict__ bias,
                                                   const int* __restrict__ batch,
                                                   unsigned short* __restrict__ outb,
                                                   float* __restrict__ S1, float* __restrict__ S2,
                                                   int M, size_t NF) {
    __shared__ unsigned short As[4][4096];   // 8 KB per wave, wave-private
    __shared__ float sstat[4][2][128];       // 4 graph slots x {s1,s2} x col
    int lane = threadIdx.x & 63;
    int wid = threadIdx.x >> 6;
    int wr = wid & 1, wc = wid >> 1;
    int quad = lane >> 4, l15 = lane & 15;
    int row0 = blockIdx.x * 64;
    unsigned short* myA = As[wid];
    f32x4 acc[2][4] = {};

    for (int i = threadIdx.x; i < 1024; i += 256) ((float*)sstat)[i] = 0.f;

    for (int s = 0; s < 4; ++s) {
        const unsigned short* Aseg = hcat + (size_t)s * NF;
        short8 stg[8];
        #pragma unroll
        for (int i = 0; i < 8; ++i) {
            int flat = i * 64 + lane;
            int r = flat >> 4, c = flat & 15;
            stg[i] = *(const short8*)(Aseg + (size_t)(row0 + wr * 32 + r) * 128 + c * 8);
        }
        #pragma unroll
        for (int i = 0; i < 8; ++i) {
            int flat = i * 64 + lane;
            int r = flat >> 4, c = flat & 15;
            *(short8*)&myA[(r * 16 + (c ^ (r & 15))) * 8] = stg[i];
        }
        #pragma unroll
        for (int kb = 0; kb < 4; ++kb) {
            int swz = ((kb * 4 + quad) ^ l15) * 8;
            short8 a0 = *(short8*)&myA[l15 * 128 + swz];
            short8 a1 = *(short8*)&myA[(16 + l15) * 128 + swz];
            const unsigned short* bb = Wf + (size_t)(((s * 4 + kb) * 2 + wc) * 4) * 512 + lane * 8;
            short8 b0 = *(const short8*)(bb + 0 * 512);
            short8 b1 = *(const short8*)(bb + 1 * 512);
            short8 b2 = *(const short8*)(bb + 2 * 512);
            short8 b3 = *(const short8*)(bb + 3 * 512);
            acc[0][0] = __builtin_amdgcn_mfma_f32_16x16x32_bf16(a0, b0, acc[0][0], 0, 0, 0);
            acc[0][1] = __builtin_amdgcn_mfma_f32_16x16x32_bf16(a0, b1, acc[0][1], 0, 0, 0);
            acc[0][2] = __builtin_amdgcn_mfma_f32_16x16x32_bf16(a0, b2, acc[0][2], 0, 0, 0);
            acc[0][3] = __builtin_amdgcn_mfma_f32_16x16x32_bf16(a0, b3, acc[0][3], 0, 0, 0);
            acc[1][0] = __builtin_amdgcn_mfma_f32_16x16x32_bf16(a1, b0, acc[1][0], 0, 0, 0);
            acc[1][1] = __builtin_amdgcn_mfma_f32_16x16x32_bf16(a1, b1, acc[1][1], 0, 0, 0);
            acc[1][2] = __builtin_amdgcn_mfma_f32_16x16x32_bf16(a1, b2, acc[1][2], 0, 0, 0);
            acc[1][3] = __builtin_amdgcn_mfma_f32_16x16x32_bf16(a1, b3, acc[1][3], 0, 0, 0);
        }
    }

    __syncthreads();   // sstat zero visible; all waves done with main loop
    int g0 = batch[row0];
    float bcol[4];
    #pragma unroll
    for (int nt = 0; nt < 4; ++nt) bcol[nt] = bias[wc * 64 + nt * 16 + l15];

    #pragma unroll
    for (int mt = 0; mt < 2; ++mt) {
        #pragma unroll
        for (int r = 0; r < 4; ++r) {
            int row = row0 + wr * 32 + mt * 16 + quad * 4 + r;
            if (row < M) {
                int d = batch[row] - g0;
                #pragma unroll
                for (int nt = 0; nt < 4; ++nt) {
                    int col = wc * 64 + nt * 16 + l15;
                    float v = acc[mt][nt][r] + bcol[nt];
                    outb[(size_t)row * 128 + col] = f2b(v);
                    if (d < 4) {
                        atomicAdd(&sstat[d][0][col], v);
                        atomicAdd(&sstat[d][1][col], v * v);
                    } else {
                        atomicAdd(&S1[(size_t)(g0 + d) * 128 + col], v);
                        atomicAdd(&S2[(size_t)(g0 + d) * 128 + col], v * v);
                    }
                }
            }
        }
    }
    __syncthreads();
    int span = batch[min(row0 + 63, M - 1)] - g0;
    int lim = (min(span, 3) + 1) * 128;
    for (int i = threadIdx.x; i < lim; i += 256) {
        int d = i >> 7, c = i & 127;
        atomicAdd(&S1[(size_t)(g0 + d) * 128 + c], sstat[d][0][c]);
        atomicAdd(&S2[(size_t)(g0 + d) * 128 + c], sstat[d][1][c]);
    }
}

// ---------------- fused finalize + normalize + relu + residual ----------------
// Reads raw S1/S2 (L2-hot), computes mean/var/scale inline; outb & y read as bf16.
__global__ void final_kernel(const ushort4* __restrict__ yb, const ushort4* __restrict__ ob,
                             const int* __restrict__ batch, const float* __restrict__ S1,
                             const float* __restrict__ S2, const int* __restrict__ gstart,
                             const float* __restrict__ gnw, const float* __restrict__ gnb,
                             const float* __restrict__ gms,
                             float4* __restrict__ res, int n) {
    int idx = blockIdx.x * blockDim.x + threadIdx.x;  // over n*32 groups of 4 feats
    if (idx >= n * 32) return;
    int node = idx >> 5;
    int q = idx & 31;
    int g = batch[node];
    float rc = 1.f / fmaxf((float)(gstart[g + 1] - gstart[g]), 1.f);
    int base = g * 128 + q * 4;
    float4 s1 = *(const float4*)&S1[base];
    float4 s2 = *(const float4*)&S2[base];
    float4 w  = *(const float4*)&gnw[q * 4];
    float4 bb = *(const float4*)&gnb[q * 4];
    float4 sc = *(const float4*)&gms[q * 4];
    ushort4 yv = yb[idx];
    ushort4 ov = ob[idx];
    float4 r;
    {
        float m = s1.x * rc, e2 = s2.x * rc, s = sc.x;
        float var = e2 - (2.f * s - s * s) * m * m;
        float A = w.x * rsqrtf(var + GN_EPS);
        r.x = b2f(yv.x) + fmaxf(0.f, (b2f(ov.x) - s * m) * A + bb.x);
    }
    {
        float m = s1.y * rc, e2 = s2.y * rc, s = sc.y;
        float var = e2 - (2.f * s - s * s) * m * m;
        float A = w.y * rsqrtf(var + GN_EPS);
        r.y = b2f(yv.y) + fmaxf(0.f, (b2f(ov.y) - s * m) * A + bb.y);
    }
    {
        float m = s1.z * rc, e2 = s2.z * rc, s = sc.z;
        float var = e2 - (2.f * s - s * s) * m * m;
        float A = w.z * rsqrtf(var + GN_EPS);
        r.z = b2f(yv.z) + fmaxf(0.f, (b2f(ov.z) - s * m) * A + bb.z);
    }
    {
        float m = s1.w * rc, e2 = s2.w * rc, s = sc.w;
        float var = e2 - (2.f * s - s * s) * m * m;
        float A = w.w * rsqrtf(var + GN_EPS);
        r.w = b2f(yv.w) + fmaxf(0.f, (b2f(ov.w) - s * m) * A + bb.w);
    }
    res[idx] = r;
}

extern "C" void kernel_launch(void* const* d_in, const int* in_sizes, int n_in,
                              void* d_out, int out_size, void* d_ws, size_t ws_size,
                              hipStream_t stream) {
    const float* y     = (const float*)d_in[0];
    const int*   ei    = (const int*)d_in[1];
    const float* ew    = (const float*)d_in[2];
    const int*   batch = (const int*)d_in[3];
    const float* tag_w = (const float*)d_in[4];
    const float* tag_b = (const float*)d_in[5];
    const float* gnw   = (const float*)d_in[6];
    const float* gnb   = (const float*)d_in[7];
    const float* gms   = (const float*)d_in[8];
    float* res = (float*)d_out;

    const int N = in_sizes[0] / F;
    const int E = in_sizes[1] / 2;
    const size_t NF = (size_t)N * F;

    // ---- workspace layout (zero-init region first, one memset) ----
    char* p = (char*)d_ws;
    unsigned long long* packed = (unsigned long long*)p; p += (size_t)N * 8;
    float* S1 = (float*)p;       p += (size_t)GRAPHS * F * 4;
    float* S2 = (float*)p;       p += (size_t)GRAPHS * F * 4;
    size_t zeroBytes = (size_t)(p - (char*)d_ws);
    int*   gstart = (int*)p;     p += 512;
    float* dinv = (float*)p;     p += (size_t)N * 4;
    int*   offs = (int*)p;       p += (size_t)(N + 4) * 4;
    int*   blockSums = (int*)p;  p += 4096;
    unsigned short* rank = (unsigned short*)p; p += ((size_t)E * 2 + 15) & ~15ull;
    unsigned* csr = (unsigned*)p; p += (size_t)E * 4;
    unsigned short* Wf = (unsigned short*)p; p += 4 * 128 * 128 * 2;
    unsigned short* hcat = (unsigned short*)p; p += NF * 2 * 4;   // 4 bf16 slices
    unsigned short* outb = (unsigned short*)p; p += NF * 2;        // bf16; also OOB-read pad
    p += 4096;                                                     // extra pad

    hipMemsetAsync(d_ws, 0, zeroBytes, stream);

    int eb = (E + 255) / 256;
    int sb = (N + SCAN_B - 1) / SCAN_B;
    int n4 = N * 32;
    int fb = (n4 + 255) / 256;
    int wb = (4 * 128 * 128) / 256;

    unsigned short* hs0 = hcat;
    unsigned short* hs1 = hcat + NF;
    unsigned short* hs2 = hcat + 2 * NF;
    unsigned short* hs3 = hcat + 3 * NF;

    prep_kernel<<<eb + fb + wb, 256, 0, stream>>>(ei, ew, packed, rank, E, eb,
                                                  (const float4*)y, (ushort4*)hs0, n4, fb,
                                                  tag_w, Wf);
    node_prep_kernel<<<sb, SCAN_B, 0, stream>>>(packed, dinv, batch, gstart, offs, blockSums, N);
    scan3_kernel<<<sb, SCAN_B, 0, stream>>>(offs, blockSums, N, E, sb);
    scatter_kernel<<<eb, 256, 0, stream>>>(ei, ew, dinv, offs, rank, csr, E);

    int hb = (N + 3) / 4;
    hop_kernel<<<hb, 256, 0, stream>>>(hs0, hs1, offs, csr, dinv, N);
    hop_kernel<<<hb, 256, 0, stream>>>(hs1, hs2, offs, csr, dinv, N);
    hop_kernel<<<hb, 256, 0, stream>>>(hs2, hs3, offs, csr, dinv, N);

    gemm_kernel<<<(N + 63) / 64, 256, 0, stream>>>(hcat, Wf, tag_b, batch, outb, S1, S2, N, NF);

    final_kernel<<<(N * 32 + 255) / 256, 256, 0, stream>>>((const ushort4*)hs0, (const ushort4*)outb,
                                                           batch, S1, S2, gstart, gnw, gnb, gms,
                                                           (float4*)res, N);
}

// Round 10
// 261.606 us; speedup vs baseline: 1.2167x; 1.2167x over previous
//
#include <hip/hip_runtime.h>

#define F 128
#define GRAPHS 64
#define GN_EPS 1e-5f
#define SCAN_B 256

typedef short short8 __attribute__((ext_vector_type(8)));
typedef float f32x4 __attribute__((ext_vector_type(4)));

__device__ __forceinline__ unsigned short f2b(float f) {      // fp32 -> bf16 RNE
    unsigned u = __float_as_uint(f);
    unsigned r = (u + 0x7fffu + ((u >> 16) & 1u)) >> 16;
    return (unsigned short)r;
}
__device__ __forceinline__ float b2f(unsigned short h) {      // bf16 -> fp32
    return __uint_as_float(((unsigned)h) << 16);
}

// ---------------- fused front-end: [deg | f2b | wcvt] (all read only inputs) --------
__global__ void prep_kernel(const int* __restrict__ ei, const float* __restrict__ ew,
                            unsigned long long* __restrict__ packed,
                            unsigned short* __restrict__ rank, int E, int ebl,
                            const float4* __restrict__ y, ushort4* __restrict__ hs0,
                            int n4, int fbl,
                            const float* __restrict__ tw, unsigned short* __restrict__ wf) {
    int b = blockIdx.x;
    if (b < ebl) {                                   // ---- deg ----
        int e = b * 256 + threadIdx.x;
        if (e < E) {
            int dst = ei[E + e];
            unsigned q = (unsigned)(ew[e] * 16777216.0f + 0.5f);
            unsigned long long old =
                atomicAdd(&packed[dst], (1ull << 40) | (unsigned long long)q);
            rank[e] = (unsigned short)(old >> 40);
        }
    } else if (b < ebl + fbl) {                      // ---- f2b ----
        int i = (b - ebl) * 256 + threadIdx.x;
        if (i < n4) {
            float4 v = y[i];
            hs0[i] = make_ushort4(f2b(v.x), f2b(v.y), f2b(v.z), f2b(v.w));
        }
    } else {                                         // ---- wcvt ----
        int i = (b - ebl - fbl) * 256 + threadIdx.x; // over 4*128*128 = 65536
        int seg = i >> 14;
        int r = i & 16383;
        int kb = r >> 12;
        int wc = (r >> 11) & 1;
        int nt = (r >> 9) & 3;
        int lane = (r >> 3) & 63;
        int j = i & 7;
        int k = kb * 32 + (lane >> 4) * 8 + j;
        int n = wc * 64 + nt * 16 + (lane & 15);
        wf[i] = f2b(tw[seg * 16384 + k * 128 + n]);
    }
}

// ---------------- fused: decode packed -> dinv, graph starts, block-local scan ------
__global__ void node_prep_kernel(const unsigned long long* __restrict__ packed,
                                 float* __restrict__ dinv, const int* __restrict__ batch,
                                 int* __restrict__ gstart, int* __restrict__ excl,
                                 int* __restrict__ blockSums, int n) {
    __shared__ int s[SCAN_B];
    int i = blockIdx.x * SCAN_B + threadIdx.x;
    int v = 0;
    if (i < n) {
        unsigned long long p = packed[i];
        v = (int)(p >> 40);
        float d = (float)(p & 0xFFFFFFFFFFull) * 5.9604644775390625e-8f;  // / 2^24
        dinv[i] = (d > 0.f) ? rsqrtf(fmaxf(d, 1e-30f)) : 0.f;
        int b = batch[i];
        if (i == 0) {
            for (int g = 0; g <= b; ++g) gstart[g] = 0;
        } else {
            int bp = batch[i - 1];
            for (int g = bp + 1; g <= b; ++g) gstart[g] = i;
        }
        if (i == n - 1) {
            for (int g = b + 1; g <= GRAPHS; ++g) gstart[g] = n;
        }
    }
    s[threadIdx.x] = v;
    __syncthreads();
    for (int off = 1; off < SCAN_B; off <<= 1) {
        int t = (threadIdx.x >= off) ? s[threadIdx.x - off] : 0;
        __syncthreads();
        s[threadIdx.x] += t;
        __syncthreads();
    }
    if (i < n) excl[i] = s[threadIdx.x] - v;
    if (threadIdx.x == SCAN_B - 1) blockSums[blockIdx.x] = s[SCAN_B - 1];
}

// ---------------- scan3 with inline block-sum scan ----------------
__global__ void scan3_kernel(int* __restrict__ offs, const int* __restrict__ blockSums,
                             int n, int total, int nb) {
    __shared__ int s[SCAN_B];
    int t = threadIdx.x;
    int v = (t < nb) ? blockSums[t] : 0;
    s[t] = v;
    __syncthreads();
    for (int off = 1; off < SCAN_B; off <<= 1) {
        int x = (t >= off) ? s[t - off] : 0;
        __syncthreads();
        s[t] += x;
        __syncthreads();
    }
    int pre = (blockIdx.x == 0) ? 0 : s[blockIdx.x - 1];
    int i = blockIdx.x * SCAN_B + t;
    if (i < n) offs[i] += pre;
    if (i == 0) offs[n] = total;
}

// ---------------- scatter edges into CSR: NO atomics, single 4B write per edge ------
__global__ void scatter_kernel(const int* __restrict__ ei, const float* __restrict__ w,
                               const float* __restrict__ dinv, const int* __restrict__ offs,
                               const unsigned short* __restrict__ rank,
                               unsigned* __restrict__ csr, int E) {
    int e = blockIdx.x * blockDim.x + threadIdx.x;
    if (e >= E) return;
    int s = ei[e];
    int d = ei[E + e];
    unsigned v = ((unsigned)s << 16) | (unsigned)f2b(dinv[s] * w[e]);
    csr[offs[d] + (int)rank[e]] = v;
}

// ---------------- one hop: node-per-wave, 16 edges in flight, 16B gathers -----------
__global__ __launch_bounds__(256) void hop_kernel(const unsigned short* __restrict__ hin,
                                                  unsigned short* __restrict__ hout,
                                                  const int* __restrict__ offs,
                                                  const unsigned* __restrict__ csr,
                                                  const float* __restrict__ dinv, int n) {
    int lane = threadIdx.x & 63;
    int node = blockIdx.x * 4 + (threadIdx.x >> 6);
    if (node >= n) return;
    int g = lane >> 4, fl = lane & 15;
    int e0 = offs[node], e1 = offs[node + 1];
    float acc[8] = {};
    for (int j = e0; j < e1; j += 16) {
        int base = j + g * 4;
        int c0 = min(base + 0, e1 - 1), c1 = min(base + 1, e1 - 1);
        int c2 = min(base + 2, e1 - 1), c3 = min(base + 3, e1 - 1);
        unsigned ed0 = csr[c0], ed1 = csr[c1], ed2 = csr[c2], ed3 = csr[c3];
        float w0 = (base + 0 < e1) ? b2f((unsigned short)(ed0 & 0xffffu)) : 0.f;
        float w1 = (base + 1 < e1) ? b2f((unsigned short)(ed1 & 0xffffu)) : 0.f;
        float w2 = (base + 2 < e1) ? b2f((unsigned short)(ed2 & 0xffffu)) : 0.f;
        float w3 = (base + 3 < e1) ? b2f((unsigned short)(ed3 & 0xffffu)) : 0.f;
        short8 h0 = *(const short8*)(hin + (size_t)(ed0 >> 16) * 128 + fl * 8);
        short8 h1 = *(const short8*)(hin + (size_t)(ed1 >> 16) * 128 + fl * 8);
        short8 h2 = *(const short8*)(hin + (size_t)(ed2 >> 16) * 128 + fl * 8);
        short8 h3 = *(const short8*)(hin + (size_t)(ed3 >> 16) * 128 + fl * 8);
        #pragma unroll
        for (int k = 0; k < 8; ++k) {
            acc[k] += w0 * b2f((unsigned short)h0[k]) + w1 * b2f((unsigned short)h1[k]);
            acc[k] += w2 * b2f((unsigned short)h2[k]) + w3 * b2f((unsigned short)h3[k]);
        }
    }
    #pragma unroll
    for (int k = 0; k < 8; ++k) {
        acc[k] += __shfl_xor(acc[k], 16);
        acc[k] += __shfl_xor(acc[k], 32);
    }
    if (lane < 16) {
        float dd = dinv[node];
        short8 o;
        #pragma unroll
        for (int k = 0; k < 8; ++k) o[k] = (short)f2b(acc[k] * dd);
        *(short8*)(hout + (size_t)node * 128 + fl * 8) = o;
    }
}

// ---------------- fused GEMM: outb(bf16) = [y|h1|h2|h3] @ [W0;W1;W2;W3] + bias -------
// R8 structure (no stats epilogue — LDS atomics there cost 87 us in R9).
__global__ __launch_bounds__(256) void gemm_kernel(const unsigned short* __restrict__ hcat,
                                                   const unsigned short* __restrict__ Wf,
                                                   const float* __restrict__ bias,
                                                   unsigned short* __restrict__ outb,
                                                   int M, size_t NF) {
    __shared__ unsigned short As[4][4096];   // 8 KB per wave, wave-private
    int lane = threadIdx.x & 63;
    int wid = threadIdx.x >> 6;
    int wr = wid & 1, wc = wid >> 1;
    int quad = lane >> 4, l15 = lane & 15;
    int row0 = blockIdx.x * 64;
    unsigned short* myA = As[wid];
    f32x4 acc[2][4] = {};

    for (int s = 0; s < 4; ++s) {
        const unsigned short* Aseg = hcat + (size_t)s * NF;
        short8 stg[8];
        #pragma unroll
        for (int i = 0; i < 8; ++i) {
            int flat = i * 64 + lane;
            int r = flat >> 4, c = flat & 15;
            stg[i] = *(const short8*)(Aseg + (size_t)(row0 + wr * 32 + r) * 128 + c * 8);
        }
        #pragma unroll
        for (int i = 0; i < 8; ++i) {
            int flat = i * 64 + lane;
            int r = flat >> 4, c = flat & 15;
            *(short8*)&myA[(r * 16 + (c ^ (r & 15))) * 8] = stg[i];
        }
        #pragma unroll
        for (int kb = 0; kb < 4; ++kb) {
            int swz = ((kb * 4 + quad) ^ l15) * 8;
            short8 a0 = *(short8*)&myA[l15 * 128 + swz];
            short8 a1 = *(short8*)&myA[(16 + l15) * 128 + swz];
            const unsigned short* bb = Wf + (size_t)(((s * 4 + kb) * 2 + wc) * 4) * 512 + lane * 8;
            short8 b0 = *(const short8*)(bb + 0 * 512);
            short8 b1 = *(const short8*)(bb + 1 * 512);
            short8 b2 = *(const short8*)(bb + 2 * 512);
            short8 b3 = *(const short8*)(bb + 3 * 512);
            acc[0][0] = __builtin_amdgcn_mfma_f32_16x16x32_bf16(a0, b0, acc[0][0], 0, 0, 0);
            acc[0][1] = __builtin_amdgcn_mfma_f32_16x16x32_bf16(a0, b1, acc[0][1], 0, 0, 0);
            acc[0][2] = __builtin_amdgcn_mfma_f32_16x16x32_bf16(a0, b2, acc[0][2], 0, 0, 0);
            acc[0][3] = __builtin_amdgcn_mfma_f32_16x16x32_bf16(a0, b3, acc[0][3], 0, 0, 0);
            acc[1][0] = __builtin_amdgcn_mfma_f32_16x16x32_bf16(a1, b0, acc[1][0], 0, 0, 0);
            acc[1][1] = __builtin_amdgcn_mfma_f32_16x16x32_bf16(a1, b1, acc[1][1], 0, 0, 0);
            acc[1][2] = __builtin_amdgcn_mfma_f32_16x16x32_bf16(a1, b2, acc[1][2], 0, 0, 0);
            acc[1][3] = __builtin_amdgcn_mfma_f32_16x16x32_bf16(a1, b3, acc[1][3], 0, 0, 0);
        }
    }

    #pragma unroll
    for (int mt = 0; mt < 2; ++mt) {
        #pragma unroll
        for (int r = 0; r < 4; ++r) {
            int row = row0 + wr * 32 + mt * 16 + quad * 4 + r;
            if (row < M) {
                #pragma unroll
                for (int nt = 0; nt < 4; ++nt) {
                    int col = wc * 64 + nt * 16 + l15;
                    outb[(size_t)row * 128 + col] = f2b(acc[mt][nt][r] + bias[col]);
                }
            }
        }
    }
}

// ---------------- per-graph sums S1, S2 from bf16 outb ----------------
// 256 threads = 4 node-parities x 64 feature-pairs (ushort2); sorted-batch flush trick.
#define STAT_NODES 32
__global__ __launch_bounds__(256) void stats_kernel(const unsigned* __restrict__ ob2,
                                                    const int* __restrict__ batch,
                                                    float* __restrict__ S1, float* __restrict__ S2,
                                                    int n) {
    int fp = threadIdx.x & 63;               // feature pair: feats fp*2, fp*2+1
    int par = threadIdx.x >> 6;              // 0..3
    int base = blockIdx.x * STAT_NODES;
    int n1 = min(base + STAT_NODES, n);
    int i0 = base + par;
    if (i0 >= n1) return;
    float s1a = 0.f, s2a = 0.f, s1b = 0.f, s2b = 0.f;
    int curg = batch[i0];
    for (int i = i0; i < n1; i += 4) {
        int g = batch[i];
        if (g != curg) {
            atomicAdd(&S1[curg * F + fp * 2 + 0], s1a);
            atomicAdd(&S2[curg * F + fp * 2 + 0], s2a);
            atomicAdd(&S1[curg * F + fp * 2 + 1], s1b);
            atomicAdd(&S2[curg * F + fp * 2 + 1], s2b);
            s1a = s2a = s1b = s2b = 0.f; curg = g;
        }
        unsigned v2 = ob2[(size_t)i * 64 + fp];
        float va = b2f((unsigned short)(v2 & 0xffffu));
        float vb = b2f((unsigned short)(v2 >> 16));
        s1a += va; s2a += va * va;
        s1b += vb; s2b += vb * vb;
    }
    atomicAdd(&S1[curg * F + fp * 2 + 0], s1a);
    atomicAdd(&S2[curg * F + fp * 2 + 0], s2a);
    atomicAdd(&S1[curg * F + fp * 2 + 1], s1b);
    atomicAdd(&S2[curg * F + fp * 2 + 1], s2b);
}

// ---------------- fused finalize + normalize + relu + residual ----------------
__global__ void final_kernel(const ushort4* __restrict__ yb, const ushort4* __restrict__ ob,
                             const int* __restrict__ batch, const float* __restrict__ S1,
                             const float* __restrict__ S2, const int* __restrict__ gstart,
                             const float* __restrict__ gnw, const float* __restrict__ gnb,
                             const float* __restrict__ gms,
                             float4* __restrict__ res, int n) {
    int idx = blockIdx.x * blockDim.x + threadIdx.x;  // over n*32 groups of 4 feats
    if (idx >= n * 32) return;
    int node = idx >> 5;
    int q = idx & 31;
    int g = batch[node];
    float rc = 1.f / fmaxf((float)(gstart[g + 1] - gstart[g]), 1.f);
    int base = g * 128 + q * 4;
    float4 s1 = *(const float4*)&S1[base];
    float4 s2 = *(const float4*)&S2[base];
    float4 w  = *(const float4*)&gnw[q * 4];
    float4 bb = *(const float4*)&gnb[q * 4];
    float4 sc = *(const float4*)&gms[q * 4];
    ushort4 yv = yb[idx];
    ushort4 ov = ob[idx];
    float4 r;
    {
        float m = s1.x * rc, e2 = s2.x * rc, s = sc.x;
        float var = e2 - (2.f * s - s * s) * m * m;
        float A = w.x * rsqrtf(var + GN_EPS);
        r.x = b2f(yv.x) + fmaxf(0.f, (b2f(ov.x) - s * m) * A + bb.x);
    }
    {
        float m = s1.y * rc, e2 = s2.y * rc, s = sc.y;
        float var = e2 - (2.f * s - s * s) * m * m;
        float A = w.y * rsqrtf(var + GN_EPS);
        r.y = b2f(yv.y) + fmaxf(0.f, (b2f(ov.y) - s * m) * A + bb.y);
    }
    {
        float m = s1.z * rc, e2 = s2.z * rc, s = sc.z;
        float var = e2 - (2.f * s - s * s) * m * m;
        float A = w.z * rsqrtf(var + GN_EPS);
        r.z = b2f(yv.z) + fmaxf(0.f, (b2f(ov.z) - s * m) * A + bb.z);
    }
    {
        float m = s1.w * rc, e2 = s2.w * rc, s = sc.w;
        float var = e2 - (2.f * s - s * s) * m * m;
        float A = w.w * rsqrtf(var + GN_EPS);
        r.w = b2f(yv.w) + fmaxf(0.f, (b2f(ov.w) - s * m) * A + bb.w);
    }
    res[idx] = r;
}

extern "C" void kernel_launch(void* const* d_in, const int* in_sizes, int n_in,
                              void* d_out, int out_size, void* d_ws, size_t ws_size,
                              hipStream_t stream) {
    const float* y     = (const float*)d_in[0];
    const int*   ei    = (const int*)d_in[1];
    const float* ew    = (const float*)d_in[2];
    const int*   batch = (const int*)d_in[3];
    const float* tag_w = (const float*)d_in[4];
    const float* tag_b = (const float*)d_in[5];
    const float* gnw   = (const float*)d_in[6];
    const float* gnb   = (const float*)d_in[7];
    const float* gms   = (const float*)d_in[8];
    float* res = (float*)d_out;

    const int N = in_sizes[0] / F;
    const int E = in_sizes[1] / 2;
    const size_t NF = (size_t)N * F;

    // ---- workspace layout (zero-init region first, one memset) ----
    char* p = (char*)d_ws;
    unsigned long long* packed = (unsigned long long*)p; p += (size_t)N * 8;
    float* S1 = (float*)p;       p += (size_t)GRAPHS * F * 4;
    float* S2 = (float*)p;       p += (size_t)GRAPHS * F * 4;
    size_t zeroBytes = (size_t)(p - (char*)d_ws);
    int*   gstart = (int*)p;     p += 512;
    float* dinv = (float*)p;     p += (size_t)N * 4;
    int*   offs = (int*)p;       p += (size_t)(N + 4) * 4;
    int*   blockSums = (int*)p;  p += 4096;
    unsigned short* rank = (unsigned short*)p; p += ((size_t)E * 2 + 15) & ~15ull;
    unsigned* csr = (unsigned*)p; p += (size_t)E * 4;
    unsigned short* Wf = (unsigned short*)p; p += 4 * 128 * 128 * 2;
    unsigned short* hcat = (unsigned short*)p; p += NF * 2 * 4;   // 4 bf16 slices
    unsigned short* outb = (unsigned short*)p; p += NF * 2;        // bf16; also OOB-read pad
    p += 4096;                                                     // extra pad

    hipMemsetAsync(d_ws, 0, zeroBytes, stream);

    int eb = (E + 255) / 256;
    int sb = (N + SCAN_B - 1) / SCAN_B;
    int n4 = N * 32;
    int fb = (n4 + 255) / 256;
    int wb = (4 * 128 * 128) / 256;

    unsigned short* hs0 = hcat;
    unsigned short* hs1 = hcat + NF;
    unsigned short* hs2 = hcat + 2 * NF;
    unsigned short* hs3 = hcat + 3 * NF;

    prep_kernel<<<eb + fb + wb, 256, 0, stream>>>(ei, ew, packed, rank, E, eb,
                                                  (const float4*)y, (ushort4*)hs0, n4, fb,
                                                  tag_w, Wf);
    node_prep_kernel<<<sb, SCAN_B, 0, stream>>>(packed, dinv, batch, gstart, offs, blockSums, N);
    scan3_kernel<<<sb, SCAN_B, 0, stream>>>(offs, blockSums, N, E, sb);
    scatter_kernel<<<eb, 256, 0, stream>>>(ei, ew, dinv, offs, rank, csr, E);

    int hb = (N + 3) / 4;
    hop_kernel<<<hb, 256, 0, stream>>>(hs0, hs1, offs, csr, dinv, N);
    hop_kernel<<<hb, 256, 0, stream>>>(hs1, hs2, offs, csr, dinv, N);
    hop_kernel<<<hb, 256, 0, stream>>>(hs2, hs3, offs, csr, dinv, N);

    gemm_kernel<<<(N + 63) / 64, 256, 0, stream>>>(hcat, Wf, tag_b, outb, N, NF);

    stats_kernel<<<(N + STAT_NODES - 1) / STAT_NODES, 256, 0, stream>>>((const unsigned*)outb,
                                                                        batch, S1, S2, N);

    final_kernel<<<(N * 32 + 255) / 256, 256, 0, stream>>>((const ushort4*)hs0, (const ushort4*)outb,
                                                           batch, S1, S2, gstart, gnw, gnb, gms,
                                                           (float4*)res, N);
}

// Round 11
// 247.952 us; speedup vs baseline: 1.2837x; 1.0551x over previous
//
#include <hip/hip_runtime.h>

#define F 128
#define GRAPHS 64
#define GN_EPS 1e-5f
#define SCAN_B 256
#define PB 256          // partition blocks

typedef short short8 __attribute__((ext_vector_type(8)));
typedef float f32x4 __attribute__((ext_vector_type(4)));

__device__ __forceinline__ unsigned short f2b(float f) {      // fp32 -> bf16 RNE
    unsigned u = __float_as_uint(f);
    unsigned r = (u + 0x7fffu + ((u >> 16) & 1u)) >> 16;
    return (unsigned short)r;
}
__device__ __forceinline__ float b2f(unsigned short h) {      // bf16 -> fp32
    return __uint_as_float(((unsigned)h) << 16);
}

// ---------- fused front-end: [P1 bucket-histogram | f2b | wcvt | gstart] ------------
// P1: per-block LDS histogram of dst>>8 -> hist_t[bucket*PB + block]. NO global atomics.
__global__ __launch_bounds__(256) void prep_kernel(const int* __restrict__ ei,
                            int* __restrict__ hist_t, int E, int NB, int chunk,
                            const float4* __restrict__ y, ushort4* __restrict__ hs0,
                            int n4, int fbl,
                            const float* __restrict__ tw, unsigned short* __restrict__ wf,
                            const int* __restrict__ batch, int* __restrict__ gstart, int n) {
    int b = blockIdx.x;
    if (b < PB) {                                    // ---- P1 histogram ----
        __shared__ int hist[256];
        hist[threadIdx.x] = 0;
        __syncthreads();
        int e0 = b * chunk, e1 = min(e0 + chunk, E);
        for (int e = e0 + threadIdx.x; e < e1; e += 256)
            atomicAdd(&hist[ei[E + e] >> 8], 1);
        __syncthreads();
        for (int k = threadIdx.x; k < NB; k += 256)
            hist_t[k * PB + b] = hist[k];
    } else if (b < PB + fbl) {                       // ---- f2b ----
        int i = (b - PB) * 256 + threadIdx.x;
        if (i < n4) {
            float4 v = y[i];
            hs0[i] = make_ushort4(f2b(v.x), f2b(v.y), f2b(v.z), f2b(v.w));
        }
    } else if (b < PB + fbl + 256) {                 // ---- wcvt (65536 elems) ----
        int i = (b - PB - fbl) * 256 + threadIdx.x;
        int seg = i >> 14;
        int r = i & 16383;
        int kb = r >> 12;
        int wc = (r >> 11) & 1;
        int nt = (r >> 9) & 3;
        int lane = (r >> 3) & 63;
        int j = i & 7;
        int k = kb * 32 + (lane >> 4) * 8 + j;
        int nn = wc * 64 + nt * 16 + (lane & 15);
        wf[i] = f2b(tw[seg * 16384 + k * 128 + nn]);
    } else {                                         // ---- gstart (batch sorted) ----
        int i = (b - PB - fbl - 256) * 256 + threadIdx.x;
        if (i < n) {
            int bb = batch[i];
            if (i == 0) {
                for (int g = 0; g <= bb; ++g) gstart[g] = 0;
            } else {
                int bp = batch[i - 1];
                for (int g = bp + 1; g <= bb; ++g) gstart[g] = i;
            }
            if (i == n - 1) {
                for (int g = bb + 1; g <= GRAPHS; ++g) gstart[g] = n;
            }
        }
    }
}

// ---------- scanA: block-local exclusive scan + blockSums (generic int array) --------
__global__ void scanA_kernel(const int* __restrict__ in, int* __restrict__ ex,
                             int* __restrict__ blockSums, int n) {
    __shared__ int s[SCAN_B];
    int i = blockIdx.x * SCAN_B + threadIdx.x;
    int v = (i < n) ? in[i] : 0;
    s[threadIdx.x] = v;
    __syncthreads();
    for (int off = 1; off < SCAN_B; off <<= 1) {
        int t = (threadIdx.x >= off) ? s[threadIdx.x - off] : 0;
        __syncthreads();
        s[threadIdx.x] += t;
        __syncthreads();
    }
    if (i < n) ex[i] = s[threadIdx.x] - v;
    if (threadIdx.x == SCAN_B - 1) blockSums[blockIdx.x] = s[SCAN_B - 1];
}

// ---------- scanB: inline blockSums scan + add (nb <= 256) ----------
__global__ void scanB_kernel(int* __restrict__ ex, const int* __restrict__ blockSums,
                             int n, int nb) {
    __shared__ int s[SCAN_B];
    int t = threadIdx.x;
    int v = (t < nb) ? blockSums[t] : 0;
    s[t] = v;
    __syncthreads();
    for (int off = 1; off < SCAN_B; off <<= 1) {
        int x = (t >= off) ? s[t - off] : 0;
        __syncthreads();
        s[t] += x;
        __syncthreads();
    }
    int pre = (blockIdx.x == 0) ? 0 : s[blockIdx.x - 1];
    int i = blockIdx.x * SCAN_B + t;
    if (i < n) ex[i] += pre;
}

// ---------- P2: stable partition of edges into dst-buckets (LDS cursors, no atomics) -
__global__ __launch_bounds__(256) void part_kernel(const int* __restrict__ ei,
                                                   const float* __restrict__ ew,
                                                   const int* __restrict__ ex,
                                                   uint2* __restrict__ part,
                                                   int E, int NB, int chunk) {
    __shared__ int cur[256];
    int k = blockIdx.x;
    for (int b = threadIdx.x; b < NB; b += 256) cur[b] = ex[b * PB + k];
    __syncthreads();
    int e0 = k * chunk, e1 = min(e0 + chunk, E);
    for (int e = e0 + threadIdx.x; e < e1; e += 256) {
        int dst = ei[E + e];
        int src = ei[e];
        float w = ew[e];
        int slot = atomicAdd(&cur[dst >> 8], 1);
        part[slot] = make_uint2(((unsigned)dst << 16) | (unsigned)src, __float_as_uint(w));
    }
}

// ---------- P3: per-bucket deg/dinv/offs + local CSR placement (all LDS) ------------
__global__ __launch_bounds__(256) void bucket_kernel(const uint2* __restrict__ part,
                                                     const int* __restrict__ ex,
                                                     float* __restrict__ dinv,
                                                     int* __restrict__ offs,
                                                     unsigned* __restrict__ csr,
                                                     int N, int NB, int E) {
    __shared__ float degf[256];
    __shared__ int cnte[256];
    __shared__ int scn[256];
    __shared__ int cur2[256];
    int b = blockIdx.x, t = threadIdx.x;
    degf[t] = 0.f;
    cnte[t] = 0;
    __syncthreads();
    int s0 = ex[b * PB];
    int s1 = (b + 1 < NB) ? ex[(b + 1) * PB] : E;
    for (int i = s0 + t; i < s1; i += 256) {
        uint2 p = part[i];
        int dl = (p.x >> 16) & 255;
        atomicAdd(&degf[dl], __uint_as_float(p.y));
        atomicAdd(&cnte[dl], 1);
    }
    __syncthreads();
    int v = cnte[t];
    scn[t] = v;
    __syncthreads();
    for (int off = 1; off < 256; off <<= 1) {
        int x = (t >= off) ? scn[t - off] : 0;
        __syncthreads();
        scn[t] += x;
        __syncthreads();
    }
    int node = b * 256 + t;
    int base = s0 + scn[t] - v;     // exclusive
    if (node < N) {
        float d = degf[t];
        dinv[node] = (d > 0.f) ? rsqrtf(fmaxf(d, 1e-30f)) : 0.f;
        offs[node] = base;
    }
    if (b == 0 && t == 0) offs[N] = E;
    cur2[t] = base;
    __syncthreads();
    for (int i = s0 + t; i < s1; i += 256) {
        uint2 p = part[i];
        int dl = (p.x >> 16) & 255;
        unsigned src = p.x & 0xffffu;
        int slot = atomicAdd(&cur2[dl], 1);
        csr[slot] = (src << 16) | (unsigned)f2b(__uint_as_float(p.y));
    }
}

// ---------- P4: csr weight *= dinv[src] (dinv is 200 KB -> L2-hot random reads) -----
__global__ void wfix_kernel(unsigned* __restrict__ csr, const float* __restrict__ dinv, int E) {
    int i = blockIdx.x * 256 + threadIdx.x;
    if (i >= E) return;
    unsigned v = csr[i];
    unsigned src = v >> 16;
    float w = b2f((unsigned short)(v & 0xffffu)) * dinv[src];
    csr[i] = (src << 16) | (unsigned)f2b(w);
}

// ---------- one hop: node-per-wave, 16 edges in flight, 16B gathers ----------------
__global__ __launch_bounds__(256) void hop_kernel(const unsigned short* __restrict__ hin,
                                                  unsigned short* __restrict__ hout,
                                                  const int* __restrict__ offs,
                                                  const unsigned* __restrict__ csr,
                                                  const float* __restrict__ dinv, int n) {
    int lane = threadIdx.x & 63;
    int node = blockIdx.x * 4 + (threadIdx.x >> 6);
    if (node >= n) return;
    int g = lane >> 4, fl = lane & 15;
    int e0 = offs[node], e1 = offs[node + 1];
    float acc[8] = {};
    for (int j = e0; j < e1; j += 16) {
        int base = j + g * 4;
        int c0 = min(base + 0, e1 - 1), c1 = min(base + 1, e1 - 1);
        int c2 = min(base + 2, e1 - 1), c3 = min(base + 3, e1 - 1);
        unsigned ed0 = csr[c0], ed1 = csr[c1], ed2 = csr[c2], ed3 = csr[c3];
        float w0 = (base + 0 < e1) ? b2f((unsigned short)(ed0 & 0xffffu)) : 0.f;
        float w1 = (base + 1 < e1) ? b2f((unsigned short)(ed1 & 0xffffu)) : 0.f;
        float w2 = (base + 2 < e1) ? b2f((unsigned short)(ed2 & 0xffffu)) : 0.f;
        float w3 = (base + 3 < e1) ? b2f((unsigned short)(ed3 & 0xffffu)) : 0.f;
        short8 h0 = *(const short8*)(hin + (size_t)(ed0 >> 16) * 128 + fl * 8);
        short8 h1 = *(const short8*)(hin + (size_t)(ed1 >> 16) * 128 + fl * 8);
        short8 h2 = *(const short8*)(hin + (size_t)(ed2 >> 16) * 128 + fl * 8);
        short8 h3 = *(const short8*)(hin + (size_t)(ed3 >> 16) * 128 + fl * 8);
        #pragma unroll
        for (int k = 0; k < 8; ++k) {
            acc[k] += w0 * b2f((unsigned short)h0[k]) + w1 * b2f((unsigned short)h1[k]);
            acc[k] += w2 * b2f((unsigned short)h2[k]) + w3 * b2f((unsigned short)h3[k]);
        }
    }
    #pragma unroll
    for (int k = 0; k < 8; ++k) {
        acc[k] += __shfl_xor(acc[k], 16);
        acc[k] += __shfl_xor(acc[k], 32);
    }
    if (lane < 16) {
        float dd = dinv[node];
        short8 o;
        #pragma unroll
        for (int k = 0; k < 8; ++k) o[k] = (short)f2b(acc[k] * dd);
        *(short8*)(hout + (size_t)node * 128 + fl * 8) = o;
    }
}

// ---------- fused GEMM: outb(bf16) = [y|h1|h2|h3] @ [W0;W1;W2;W3] + bias -----------
__global__ __launch_bounds__(256) void gemm_kernel(const unsigned short* __restrict__ hcat,
                                                   const unsigned short* __restrict__ Wf,
                                                   const float* __restrict__ bias,
                                                   unsigned short* __restrict__ outb,
                                                   int M, size_t NF) {
    __shared__ unsigned short As[4][4096];   // 8 KB per wave, wave-private
    int lane = threadIdx.x & 63;
    int wid = threadIdx.x >> 6;
    int wr = wid & 1, wc = wid >> 1;
    int quad = lane >> 4, l15 = lane & 15;
    int row0 = blockIdx.x * 64;
    unsigned short* myA = As[wid];
    f32x4 acc[2][4] = {};

    for (int s = 0; s < 4; ++s) {
        const unsigned short* Aseg = hcat + (size_t)s * NF;
        short8 stg[8];
        #pragma unroll
        for (int i = 0; i < 8; ++i) {
            int flat = i * 64 + lane;
            int r = flat >> 4, c = flat & 15;
            stg[i] = *(const short8*)(Aseg + (size_t)(row0 + wr * 32 + r) * 128 + c * 8);
        }
        #pragma unroll
        for (int i = 0; i < 8; ++i) {
            int flat = i * 64 + lane;
            int r = flat >> 4, c = flat & 15;
            *(short8*)&myA[(r * 16 + (c ^ (r & 15))) * 8] = stg[i];
        }
        #pragma unroll
        for (int kb = 0; kb < 4; ++kb) {
            int swz = ((kb * 4 + quad) ^ l15) * 8;
            short8 a0 = *(short8*)&myA[l15 * 128 + swz];
            short8 a1 = *(short8*)&myA[(16 + l15) * 128 + swz];
            const unsigned short* bb = Wf + (size_t)(((s * 4 + kb) * 2 + wc) * 4) * 512 + lane * 8;
            short8 b0 = *(const short8*)(bb + 0 * 512);
            short8 b1 = *(const short8*)(bb + 1 * 512);
            short8 b2 = *(const short8*)(bb + 2 * 512);
            short8 b3 = *(const short8*)(bb + 3 * 512);
            acc[0][0] = __builtin_amdgcn_mfma_f32_16x16x32_bf16(a0, b0, acc[0][0], 0, 0, 0);
            acc[0][1] = __builtin_amdgcn_mfma_f32_16x16x32_bf16(a0, b1, acc[0][1], 0, 0, 0);
            acc[0][2] = __builtin_amdgcn_mfma_f32_16x16x32_bf16(a0, b2, acc[0][2], 0, 0, 0);
            acc[0][3] = __builtin_amdgcn_mfma_f32_16x16x32_bf16(a0, b3, acc[0][3], 0, 0, 0);
            acc[1][0] = __builtin_amdgcn_mfma_f32_16x16x32_bf16(a1, b0, acc[1][0], 0, 0, 0);
            acc[1][1] = __builtin_amdgcn_mfma_f32_16x16x32_bf16(a1, b1, acc[1][1], 0, 0, 0);
            acc[1][2] = __builtin_amdgcn_mfma_f32_16x16x32_bf16(a1, b2, acc[1][2], 0, 0, 0);
            acc[1][3] = __builtin_amdgcn_mfma_f32_16x16x32_bf16(a1, b3, acc[1][3], 0, 0, 0);
        }
    }

    #pragma unroll
    for (int mt = 0; mt < 2; ++mt) {
        #pragma unroll
        for (int r = 0; r < 4; ++r) {
            int row = row0 + wr * 32 + mt * 16 + quad * 4 + r;
            if (row < M) {
                #pragma unroll
                for (int nt = 0; nt < 4; ++nt) {
                    int col = wc * 64 + nt * 16 + l15;
                    outb[(size_t)row * 128 + col] = f2b(acc[mt][nt][r] + bias[col]);
                }
            }
        }
    }
}

// ---------- per-graph sums S1, S2 from bf16 outb ----------------
#define STAT_NODES 32
__global__ __launch_bounds__(256) void stats_kernel(const unsigned* __restrict__ ob2,
                                                    const int* __restrict__ batch,
                                                    float* __restrict__ S1, float* __restrict__ S2,
                                                    int n) {
    int fp = threadIdx.x & 63;
    int par = threadIdx.x >> 6;
    int base = blockIdx.x * STAT_NODES;
    int n1 = min(base + STAT_NODES, n);
    int i0 = base + par;
    if (i0 >= n1) return;
    float s1a = 0.f, s2a = 0.f, s1b = 0.f, s2b = 0.f;
    int curg = batch[i0];
    for (int i = i0; i < n1; i += 4) {
        int g = batch[i];
        if (g != curg) {
            atomicAdd(&S1[curg * F + fp * 2 + 0], s1a);
            atomicAdd(&S2[curg * F + fp * 2 + 0], s2a);
            atomicAdd(&S1[curg * F + fp * 2 + 1], s1b);
            atomicAdd(&S2[curg * F + fp * 2 + 1], s2b);
            s1a = s2a = s1b = s2b = 0.f; curg = g;
        }
        unsigned v2 = ob2[(size_t)i * 64 + fp];
        float va = b2f((unsigned short)(v2 & 0xffffu));
        float vb = b2f((unsigned short)(v2 >> 16));
        s1a += va; s2a += va * va;
        s1b += vb; s2b += vb * vb;
    }
    atomicAdd(&S1[curg * F + fp * 2 + 0], s1a);
    atomicAdd(&S2[curg * F + fp * 2 + 0], s2a);
    atomicAdd(&S1[curg * F + fp * 2 + 1], s1b);
    atomicAdd(&S2[curg * F + fp * 2 + 1], s2b);
}

// ---------- fused finalize + normalize + relu + residual ----------------
__global__ void final_kernel(const ushort4* __restrict__ yb, const ushort4* __restrict__ ob,
                             const int* __restrict__ batch, const float* __restrict__ S1,
                             const float* __restrict__ S2, const int* __restrict__ gstart,
                             const float* __restrict__ gnw, const float* __restrict__ gnb,
                             const float* __restrict__ gms,
                             float4* __restrict__ res, int n) {
    int idx = blockIdx.x * blockDim.x + threadIdx.x;
    if (idx >= n * 32) return;
    int node = idx >> 5;
    int q = idx & 31;
    int g = batch[node];
    float rc = 1.f / fmaxf((float)(gstart[g + 1] - gstart[g]), 1.f);
    int base = g * 128 + q * 4;
    float4 s1 = *(const float4*)&S1[base];
    float4 s2 = *(const float4*)&S2[base];
    float4 w  = *(const float4*)&gnw[q * 4];
    float4 bb = *(const float4*)&gnb[q * 4];
    float4 sc = *(const float4*)&gms[q * 4];
    ushort4 yv = yb[idx];
    ushort4 ov = ob[idx];
    float4 r;
    {
        float m = s1.x * rc, e2 = s2.x * rc, s = sc.x;
        float var = e2 - (2.f * s - s * s) * m * m;
        float A = w.x * rsqrtf(var + GN_EPS);
        r.x = b2f(yv.x) + fmaxf(0.f, (b2f(ov.x) - s * m) * A + bb.x);
    }
    {
        float m = s1.y * rc, e2 = s2.y * rc, s = sc.y;
        float var = e2 - (2.f * s - s * s) * m * m;
        float A = w.y * rsqrtf(var + GN_EPS);
        r.y = b2f(yv.y) + fmaxf(0.f, (b2f(ov.y) - s * m) * A + bb.y);
    }
    {
        float m = s1.z * rc, e2 = s2.z * rc, s = sc.z;
        float var = e2 - (2.f * s - s * s) * m * m;
        float A = w.z * rsqrtf(var + GN_EPS);
        r.z = b2f(yv.z) + fmaxf(0.f, (b2f(ov.z) - s * m) * A + bb.z);
    }
    {
        float m = s1.w * rc, e2 = s2.w * rc, s = sc.w;
        float var = e2 - (2.f * s - s * s) * m * m;
        float A = w.w * rsqrtf(var + GN_EPS);
        r.w = b2f(yv.w) + fmaxf(0.f, (b2f(ov.w) - s * m) * A + bb.w);
    }
    res[idx] = r;
}

extern "C" void kernel_launch(void* const* d_in, const int* in_sizes, int n_in,
                              void* d_out, int out_size, void* d_ws, size_t ws_size,
                              hipStream_t stream) {
    const float* y     = (const float*)d_in[0];
    const int*   ei    = (const int*)d_in[1];
    const float* ew    = (const float*)d_in[2];
    const int*   batch = (const int*)d_in[3];
    const float* tag_w = (const float*)d_in[4];
    const float* tag_b = (const float*)d_in[5];
    const float* gnw   = (const float*)d_in[6];
    const float* gnb   = (const float*)d_in[7];
    const float* gms   = (const float*)d_in[8];
    float* res = (float*)d_out;

    const int N = in_sizes[0] / F;
    const int E = in_sizes[1] / 2;
    const size_t NF = (size_t)N * F;
    const int NB = (N + 255) >> 8;           // dst buckets of 256 nodes
    const int NH = NB * PB;                  // histogram entries
    const int chunk = (E + PB - 1) / PB;

    // ---- workspace layout (zero-init region first, one small memset) ----
    char* p = (char*)d_ws;
    float* S1 = (float*)p;       p += (size_t)GRAPHS * F * 4;
    float* S2 = (float*)p;       p += (size_t)GRAPHS * F * 4;
    size_t zeroBytes = (size_t)(p - (char*)d_ws);
    int*   gstart = (int*)p;     p += 512;
    float* dinv = (float*)p;     p += (size_t)N * 4;
    int*   offs = (int*)p;       p += (size_t)(N + 4) * 4;
    int*   hist_t = (int*)p;     p += (size_t)NH * 4;
    int*   ex = (int*)p;         p += (size_t)(NH + 4) * 4;
    int*   blockSums = (int*)p;  p += 4096;
    uint2* part = (uint2*)p;     p += (size_t)E * 8;
    unsigned* csr = (unsigned*)p; p += (size_t)E * 4;
    unsigned short* Wf = (unsigned short*)p; p += 4 * 128 * 128 * 2;
    unsigned short* hcat = (unsigned short*)p; p += NF * 2 * 4;   // 4 bf16 slices
    unsigned short* outb = (unsigned short*)p; p += NF * 2;        // bf16; OOB-read pad
    p += 4096;

    hipMemsetAsync(d_ws, 0, zeroBytes, stream);

    int n4 = N * 32;
    int fb = (n4 + 255) / 256;
    int gb = (N + 255) / 256;
    int hsb = (NH + SCAN_B - 1) / SCAN_B;    // 196

    unsigned short* hs0 = hcat;
    unsigned short* hs1 = hcat + NF;
    unsigned short* hs2 = hcat + 2 * NF;
    unsigned short* hs3 = hcat + 3 * NF;

    prep_kernel<<<PB + fb + 256 + gb, 256, 0, stream>>>(ei, hist_t, E, NB, chunk,
                                                        (const float4*)y, (ushort4*)hs0, n4, fb,
                                                        tag_w, Wf, batch, gstart, N);
    scanA_kernel<<<hsb, SCAN_B, 0, stream>>>(hist_t, ex, blockSums, NH);
    scanB_kernel<<<hsb, SCAN_B, 0, stream>>>(ex, blockSums, NH, hsb);
    part_kernel<<<PB, 256, 0, stream>>>(ei, ew, ex, part, E, NB, chunk);
    bucket_kernel<<<NB, 256, 0, stream>>>(part, ex, dinv, offs, csr, N, NB, E);
    wfix_kernel<<<(E + 255) / 256, 256, 0, stream>>>(csr, dinv, E);

    int hb = (N + 3) / 4;
    hop_kernel<<<hb, 256, 0, stream>>>(hs0, hs1, offs, csr, dinv, N);
    hop_kernel<<<hb, 256, 0, stream>>>(hs1, hs2, offs, csr, dinv, N);
    hop_kernel<<<hb, 256, 0, stream>>>(hs2, hs3, offs, csr, dinv, N);

    gemm_kernel<<<(N + 63) / 64, 256, 0, stream>>>(hcat, Wf, tag_b, outb, N, NF);

    stats_kernel<<<(N + STAT_NODES - 1) / STAT_NODES, 256, 0, stream>>>((const unsigned*)outb,
                                                                        batch, S1, S2, N);

    final_kernel<<<(N * 32 + 255) / 256, 256, 0, stream>>>((const ushort4*)hs0, (const ushort4*)outb,
                                                           batch, S1, S2, gstart, gnw, gnb, gms,
                                                           (float4*)res, N);
}